// Round 5
// baseline (186.424 us; speedup 1.0000x reference)
//
#include <hip/hip_runtime.h>
#include <math.h>

#define BB 8
#define CC 1024
#define HW 48
#define NN 2304   // 48*48
#define MM 2304
#define KK 32

typedef __attribute__((ext_vector_type(8))) short short8v;
typedef __attribute__((ext_vector_type(4))) float f32x4;

__device__ __forceinline__ unsigned short f2bf(float f) {
    unsigned u = __float_as_uint(f);
    return (unsigned short)((u + 0x7FFFu + ((u >> 16) & 1u)) >> 16);
}

// ---------------- Kernel 1: antialiased linear resize 384->48, threshold > 0.5 ----------------
__global__ void mask_kernel(const float* __restrict__ rm, float* __restrict__ mask) {
    int t = blockIdx.x * 256 + threadIdx.x;
    if (t >= BB * NN) return;
    int b = t / NN, p = t % NN;
    int y = p / HW, x = p % HW;
    const float* src = rm + (size_t)b * 384 * 384;

    int jx0 = 8 * x - 4;
    float wx[16];
    float wxs = 0.f;
    #pragma unroll
    for (int dx = 0; dx < 16; ++dx) {
        int jx = jx0 + dx;
        float w = 1.0f - fabsf((float)dx - 7.5f) * 0.125f;
        if (jx >= 0 && jx < 384) { wx[dx] = w; wxs += w; } else wx[dx] = 0.f;
    }
    int jy0 = 8 * y - 4;
    float acc = 0.f, wys = 0.f;
    for (int dy = 0; dy < 16; ++dy) {
        int jy = jy0 + dy;
        if (jy < 0 || jy >= 384) continue;
        float wy = 1.0f - fabsf((float)dy - 7.5f) * 0.125f;
        wys += wy;
        const float* row = src + (size_t)jy * 384;
        float rs = 0.f;
        #pragma unroll
        for (int dx = 0; dx < 16; ++dx) {
            if (wx[dx] > 0.f) rs += wx[dx] * row[jx0 + dx];
        }
        acc += wy * rs;
    }
    float v = acc / (wys * wxs);
    mask[t] = (v > 0.5f) ? 1.0f : 0.0f;
}

// ---------------- Kernel 2: scores[b,n] = sum_m corr[b,n,m]*mask[b,m] ----------------
__global__ void scores_kernel(const float* __restrict__ corr, const float* __restrict__ mask,
                              float* __restrict__ scores) {
    int wave = threadIdx.x >> 6, lane = threadIdx.x & 63;
    int row = blockIdx.x * 4 + wave;
    int b = row / NN, n = row % NN;
    const float4* cr = (const float4*)(corr + ((size_t)b * NN + n) * MM);
    const float4* mr = (const float4*)(mask + (size_t)b * MM);
    float acc = 0.f;
    #pragma unroll
    for (int it = 0; it < 9; ++it) {
        int i = it * 64 + lane;
        float4 cv = cr[i];
        float4 mv = mr[i];
        acc += cv.x * mv.x + cv.y * mv.y + cv.z * mv.z + cv.w * mv.w;
    }
    #pragma unroll
    for (int off = 32; off >= 1; off >>= 1) acc += __shfl_down(acc, off);
    if (lane == 0) scores[row] = acc;
}

// ---------------- Kernel 3: fused topk(+gather) and weight conversion ----------------
// blocks 0..7: per-batch top-32 (512 threads, register-resident values) + gather st16.
// blocks 8..39: gw/glw -> bf16.
__global__ __launch_bounds__(512) void topk_gather_wconv(
    const float* __restrict__ scores, const float* __restrict__ cur,
    const float* __restrict__ gw, const float* __restrict__ glw,
    unsigned short* __restrict__ st, unsigned short* __restrict__ gwh,
    unsigned short* __restrict__ glwh)
{
    int blk = blockIdx.x, t = threadIdx.x;
    if (blk >= 8) {
        int e = (blk - 8) * 512 + t;           // 0..16383
        gwh[e] = f2bf(gw[e]);
        gwh[e + 16384] = f2bf(gw[e + 16384]);
        glwh[e] = f2bf(glw[e]);
        glwh[e + 16384] = f2bf(glw[e + 16384]);
        return;
    }
    int b = blk;
    float v[5];
    #pragma unroll
    for (int j = 0; j < 5; ++j) {
        int e = t + 512 * j;
        v[j] = (e < NN) ? scores[b * NN + e] : -INFINITY;
    }
    __shared__ float wv[8]; __shared__ int wi[8];
    __shared__ int idxL[KK];
    __shared__ int bcast;
    int lane = t & 63, w = t >> 6;
    for (int it = 0; it < KK; ++it) {
        float bv = -INFINITY; int bi = 1 << 30;
        #pragma unroll
        for (int j = 0; j < 5; ++j) {          // ascending e -> lowest index on ties
            int e = t + 512 * j;
            if (v[j] > bv) { bv = v[j]; bi = e; }
        }
        #pragma unroll
        for (int off = 32; off >= 1; off >>= 1) {
            float ov = __shfl_down(bv, off);
            int   oi = __shfl_down(bi, off);
            if (ov > bv || (ov == bv && oi < bi)) { bv = ov; bi = oi; }
        }
        if (lane == 0) { wv[w] = bv; wi[w] = bi; }
        __syncthreads();
        if (t == 0) {
            #pragma unroll
            for (int u = 1; u < 8; ++u)
                if (wv[u] > bv || (wv[u] == bv && wi[u] < bi)) { bv = wv[u]; bi = wi[u]; }
            idxL[it] = bi;
            bcast = bi;
        }
        __syncthreads();
        int W = bcast;
        #pragma unroll
        for (int j = 0; j < 5; ++j)
            if (t + 512 * j == W) v[j] = -INFINITY;
    }
    // gather st[b][k][c] = bf16(cur[b,c,idx[k]])
    const float* curb = cur + (size_t)b * CC * NN;
    unsigned short* stb = st + b * (KK * CC);
    for (int e = t; e < KK * CC; e += 512) {
        int k = e >> 10, c = e & (CC - 1);
        stb[e] = f2bf(curb[(size_t)c * NN + idxL[k]]);
    }
}

// ---------------- Kernel 4: fused MFMA, stage-once structure ----------------
// grid 8*144 (XCD-chunked: b = hw&7), 256 thr = 4 waves.
// XT[16 n][1024 c] bf16 staged ONCE (swizzled). Pass A: wave w -> (mat=w>>1: st|glw,
// mrow=w&1) 16x16 tile over K=1024, A-frags straight from global (L2-hot).
// Pass B: wave w owns groups k=8w..8w+7; PART reduce aliased onto dead XT space.
__global__ __launch_bounds__(256) void fused_mfma(
    const float* __restrict__ cur, const unsigned short* __restrict__ st16,
    const unsigned short* __restrict__ gwh, const unsigned short* __restrict__ glwh,
    const float* __restrict__ gb, const float* __restrict__ glb,
    float* __restrict__ out)
{
    __shared__ __align__(16) char SMEM[32768];      // XT (pass A/B) then PART (epilogue)
    unsigned short* XT = (unsigned short*)SMEM;     // [16 n][1024 c], row 2048B, swizzled
    float (*PART)[2][256] = (float (*)[2][256])SMEM;
    __shared__ float SIL[32][18];
    __shared__ float MS[16];
    __shared__ float GBL[CC];
    __shared__ float GLBL[32];

    int hw = blockIdx.x;
    int b = hw & 7;                 // XCD-chunked: XCD j owns batch j
    int n0 = (hw >> 3) * 16;
    int t = threadIdx.x;
    int w = t >> 6, l = t & 63;
    int mrow = w & 1, mat = w >> 1;
    int nrow = l & 15, kq = l >> 4;

    for (int i = t; i < CC; i += 256) GBL[i] = gb[i];
    if (t < 32) GLBL[t] = glb[t];

    // ---- stage XT once: 16 independent float4 loads per thread ----
    const float* curb = cur + (size_t)b * CC * NN;
    int nq = t & 3, ci0 = t >> 2;
    #pragma unroll
    for (int q = 0; q < 8; ++q) {
        int ci = ci0 + 64 * q;                 // c-pair 0..511
        int c = 2 * ci;
        const float* p0 = curb + (size_t)c * NN + n0 + 4 * nq;
        float4 f0 = *(const float4*)p0;
        float4 f1 = *(const float4*)(p0 + NN);
        float a0[4] = {f0.x, f0.y, f0.z, f0.w};
        float a1[4] = {f1.x, f1.y, f1.z, f1.w};
        #pragma unroll
        for (int r = 0; r < 4; ++r) {
            int n = 4 * nq + r;
            unsigned pk = (unsigned)f2bf(a0[r]) | ((unsigned)f2bf(a1[r]) << 16);
            *(unsigned*)((char*)XT + n * 2048 + ((((ci >> 2) ^ (n & 7)) << 4) + ((ci & 3) << 2))) = pk;
        }
    }
    __syncthreads();

    // ---- pass A: per-wave independent 16x16 x K=1024 ----
    const char* xbase = (const char*)XT + nrow * 2048;
    const unsigned short* Abase = (mat == 0 ? st16 + (size_t)b * KK * CC : glwh)
                                  + (size_t)(16 * mrow + nrow) * CC + 8 * kq;
    f32x4 acc = {0.f, 0.f, 0.f, 0.f};
    #pragma unroll 8
    for (int cc = 0; cc < 32; ++cc) {
        short8v A = *(const short8v*)(Abase + cc * 32);
        short8v B = *(const short8v*)(xbase + (((cc * 4 + kq) ^ (nrow & 7)) << 4));
        acc = __builtin_amdgcn_mfma_f32_16x16x32_bf16(A, B, acc, 0, 0, 0);
    }

    if (mat == 0) {
        #pragma unroll
        for (int r = 0; r < 4; ++r)
            SIL[16 * mrow + 4 * kq + r][nrow] = acc[r];
    }
    __syncthreads();
    if (t < 16) {
        float s = 0.f;
        #pragma unroll
        for (int k = 0; k < 32; ++k) s += SIL[k][t];
        MS[t] = s * (1.0f / 32.0f);
    }

    // ---- pass B: grouped conv, 8 groups per wave ----
    f32x4 p0 = {0.f, 0.f, 0.f, 0.f}, p1 = {0.f, 0.f, 0.f, 0.f};
    const f32x4 zz = {0.f, 0.f, 0.f, 0.f};
    #pragma unroll
    for (int j = 0; j < 8; ++j) {
        int k = 8 * w + j;
        const unsigned short* gk = gwh + k * 1024 + 8 * kq;
        short8v A0 = *(const short8v*)(gk + nrow * 32);
        short8v A1 = *(const short8v*)(gk + (16 + nrow) * 32);
        short8v B = *(const short8v*)(xbase + (((k * 4 + kq) ^ (nrow & 7)) << 4));
        f32x4 g0 = __builtin_amdgcn_mfma_f32_16x16x32_bf16(A0, B, zz, 0, 0, 0);
        f32x4 g1 = __builtin_amdgcn_mfma_f32_16x16x32_bf16(A1, B, zz, 0, 0, 0);
        float sik = SIL[k][nrow];
        #pragma unroll
        for (int r = 0; r < 4; ++r) {
            p0[r] += sik * fmaxf(g0[r] + GBL[k * 32 + 4 * kq + r], 0.f);
            p1[r] += sik * fmaxf(g1[r] + GBL[k * 32 + 16 + 4 * kq + r], 0.f);
        }
    }
    __syncthreads();                       // all waves done reading XT before alias-write
    *(f32x4*)&PART[w][0][l * 4] = p0;
    *(f32x4*)&PART[w][1][l * 4] = p1;
    __syncthreads();

    // ---- final writes ----
    size_t ob = (size_t)b * 64 * NN + n0 + nrow;
    if (mat == 0) {
        #pragma unroll
        for (int r = 0; r < 4; ++r) {
            int li = l * 4 + r;
            float v = PART[0][mrow][li] + PART[1][mrow][li]
                    + PART[2][mrow][li] + PART[3][mrow][li];
            out[ob + (size_t)(16 * mrow + 4 * kq + r) * NN] = v;
        }
    } else {
        float msv = MS[nrow];
        #pragma unroll
        for (int r = 0; r < 4; ++r) {
            int o = 16 * mrow + 4 * kq + r;
            out[ob + (size_t)(32 + o) * NN] = fmaxf(acc[r] + GLBL[o], 0.f) * msv;
        }
    }
}

extern "C" void kernel_launch(void* const* d_in, const int* in_sizes, int n_in,
                              void* d_out, int out_size, void* d_ws, size_t ws_size,
                              hipStream_t stream) {
    const float* corr = (const float*)d_in[0];   // [B,48,48,48,48]
    const float* cur  = (const float*)d_in[1];   // [B,1024,48,48]
    const float* rm   = (const float*)d_in[2];   // [B,1,384,384]
    const float* gw   = (const float*)d_in[3];   // [32,32,32]
    const float* gb   = (const float*)d_in[4];   // [1024]
    const float* glw  = (const float*)d_in[5];   // [32,1024]
    const float* glb  = (const float*)d_in[6];   // [32]
    float* out = (float*)d_out;
    float* ws  = (float*)d_ws;

    float* mask   = ws;                                   // 18432 f32
    float* scores = mask + BB * MM;                       // 18432 f32
    unsigned short* st16 = (unsigned short*)(scores + BB * NN);  // 262144 u16
    unsigned short* gwh  = st16 + BB * KK * CC;           // 32768 u16
    unsigned short* glwh = gwh + 32768;                   // 32768 u16

    mask_kernel<<<(BB * NN + 255) / 256, 256, 0, stream>>>(rm, mask);
    scores_kernel<<<BB * NN / 4, 256, 0, stream>>>(corr, mask, scores);
    topk_gather_wconv<<<40, 512, 0, stream>>>(scores, cur, gw, glw, st16, gwh, glwh);
    fused_mfma<<<BB * (NN / 16), 256, 0, stream>>>(cur, st16, gwh, glwh, gb, glb, out);
}

// Round 7
// 143.159 us; speedup vs baseline: 1.3022x; 1.3022x over previous
//
#include <hip/hip_runtime.h>
#include <math.h>

#define BB 8
#define CC 1024
#define HW 48
#define NN 2304   // 48*48
#define MM 2304
#define KK 32

typedef __attribute__((ext_vector_type(8))) short short8v;
typedef __attribute__((ext_vector_type(4))) float f32x4;

__device__ __forceinline__ unsigned short f2bf(float f) {
    unsigned u = __float_as_uint(f);
    return (unsigned short)((u + 0x7FFFu + ((u >> 16) & 1u)) >> 16);
}

// ---------------- Kernel 1: mask (blocks 0..71) + weight bf16 conversion (72..199) ----------------
__global__ void mask_wconv_kernel(const float* __restrict__ rm, float* __restrict__ mask,
                                  const float* __restrict__ gw, const float* __restrict__ glw,
                                  unsigned short* __restrict__ gwh, unsigned short* __restrict__ glwh) {
    int blk = blockIdx.x, tt = threadIdx.x;
    if (blk >= 72) {
        int e = (blk - 72) * 256 + tt;        // 0..32767
        gwh[e] = f2bf(gw[e]);
        glwh[e] = f2bf(glw[e]);
        return;
    }
    int t = blk * 256 + tt;                    // 0..18431
    int b = t / NN, p = t % NN;
    int y = p / HW, x = p % HW;
    const float* src = rm + (size_t)b * 384 * 384;

    int jx0 = 8 * x - 4;
    float wx[16];
    float wxs = 0.f;
    #pragma unroll
    for (int dx = 0; dx < 16; ++dx) {
        int jx = jx0 + dx;
        float w = 1.0f - fabsf((float)dx - 7.5f) * 0.125f;
        if (jx >= 0 && jx < 384) { wx[dx] = w; wxs += w; } else wx[dx] = 0.f;
    }
    int jy0 = 8 * y - 4;
    float acc = 0.f, wys = 0.f;
    for (int dy = 0; dy < 16; ++dy) {
        int jy = jy0 + dy;
        if (jy < 0 || jy >= 384) continue;
        float wy = 1.0f - fabsf((float)dy - 7.5f) * 0.125f;
        wys += wy;
        const float* row = src + (size_t)jy * 384;
        float rs = 0.f;
        #pragma unroll
        for (int dx = 0; dx < 16; ++dx) {
            if (wx[dx] > 0.f) rs += wx[dx] * row[jx0 + dx];
        }
        acc += wy * rs;
    }
    float v = acc / (wys * wxs);
    mask[t] = (v > 0.5f) ? 1.0f : 0.0f;
}

// ---------------- Kernel 2: scores[b,n] = sum_m corr[b,n,m]*mask[b,m] ----------------
__global__ void scores_kernel(const float* __restrict__ corr, const float* __restrict__ mask,
                              float* __restrict__ scores) {
    int wave = threadIdx.x >> 6, lane = threadIdx.x & 63;
    int row = blockIdx.x * 4 + wave;
    int b = row / NN, n = row % NN;
    const float4* cr = (const float4*)(corr + ((size_t)b * NN + n) * MM);
    const float4* mr = (const float4*)(mask + (size_t)b * MM);
    float acc = 0.f;
    #pragma unroll
    for (int it = 0; it < 9; ++it) {
        int i = it * 64 + lane;
        float4 cv = cr[i];
        float4 mv = mr[i];
        acc += cv.x * mv.x + cv.y * mv.y + cv.z * mv.z + cv.w * mv.w;
    }
    #pragma unroll
    for (int off = 32; off >= 1; off >>= 1) acc += __shfl_down(acc, off);
    if (lane == 0) scores[row] = acc;
}

// ---------------- Kernel 3: wave-local top-32 (1 wave per batch, no barriers) ----------------
// 2 blocks x 256 threads = 8 waves; wave w of block blk handles batch blk*4+w.
// 36 score values per lane in registers; lazy local-max (only winner lane rescans).
__global__ __launch_bounds__(256) void topk_kernel(const float* __restrict__ scores,
                                                   int* __restrict__ idxo) {
    int w = threadIdx.x >> 6, lane = threadIdx.x & 63;
    int b = blockIdx.x * 4 + w;
    const float* s = scores + b * NN;
    float lv[36];
    #pragma unroll
    for (int j = 0; j < 36; ++j) lv[j] = s[lane + 64 * j];   // coalesced
    float lmax = -INFINITY; int lj = 0;
    #pragma unroll
    for (int j = 0; j < 36; ++j) if (lv[j] > lmax) { lmax = lv[j]; lj = j; }  // ascending: lowest idx on tie
    int lidx = lane + 64 * lj;

    for (int it = 0; it < KK; ++it) {
        float bv = lmax; int bi = lidx;
        #pragma unroll
        for (int off = 32; off >= 1; off >>= 1) {
            float ov = __shfl_down(bv, off);
            int   oi = __shfl_down(bi, off);
            if (ov > bv || (ov == bv && oi < bi)) { bv = ov; bi = oi; }
        }
        int W = __shfl(bi, 0);                 // broadcast winner global index
        if (lane == 0) idxo[b * KK + it] = W;
        if ((W & 63) == lane) {                // only winner lane rescans its 36
            int wj = W >> 6;
            float nmax = -INFINITY; int nj = 0;
            #pragma unroll
            for (int j = 0; j < 36; ++j) {     // compile-time j: stays in registers
                if (j == wj) lv[j] = -INFINITY;
                if (lv[j] > nmax) { nmax = lv[j]; nj = j; }
            }
            lmax = nmax; lidx = lane + 64 * nj;
        }
    }
}

// ---------------- Kernel 4: gather st16[b][k][c] = bf16(cur[b,c,idx[b,k]]) ----------------
__global__ void gather_kernel(const float* __restrict__ cur, const int* __restrict__ idx,
                              unsigned short* __restrict__ st) {
    int e = blockIdx.x * 256 + threadIdx.x;    // 0..262143
    int c = e & (CC - 1); int bk = e >> 10; int k = bk & 31; int b = bk >> 5;
    st[e] = f2bf(cur[((size_t)b * CC + c) * NN + idx[b * KK + k]]);
}

// ---------------- Kernel 5: fused MFMA, stage-once structure ----------------
// grid 8*144 (XCD-chunked: b = hw&7), 256 thr = 4 waves.
// XT[16 n][1024 c] bf16 staged ONCE (swizzled). Pass A: wave w -> (mat=w>>1: st|glw,
// mrow=w&1) 16x16 tile over K=1024, A-frags straight from global (L2-hot).
// Pass B: wave w owns groups k=8w..8w+7; PART reduce aliased onto dead XT space.
__global__ __launch_bounds__(256) void fused_mfma(
    const float* __restrict__ cur, const unsigned short* __restrict__ st16,
    const unsigned short* __restrict__ gwh, const unsigned short* __restrict__ glwh,
    const float* __restrict__ gb, const float* __restrict__ glb,
    float* __restrict__ out)
{
    __shared__ __align__(16) char SMEM[32768];      // XT (pass A/B) then PART (epilogue)
    unsigned short* XT = (unsigned short*)SMEM;     // [16 n][1024 c], row 2048B, swizzled
    float (*PART)[2][256] = (float (*)[2][256])SMEM;
    __shared__ float SIL[32][18];
    __shared__ float MS[16];
    __shared__ float GBL[CC];
    __shared__ float GLBL[32];

    int hw = blockIdx.x;
    int b = hw & 7;                 // XCD-chunked: XCD j owns batch j
    int n0 = (hw >> 3) * 16;
    int t = threadIdx.x;
    int w = t >> 6, l = t & 63;
    int mrow = w & 1, mat = w >> 1;
    int nrow = l & 15, kq = l >> 4;

    for (int i = t; i < CC; i += 256) GBL[i] = gb[i];
    if (t < 32) GLBL[t] = glb[t];

    // ---- stage XT once: 16 independent float4 loads per thread ----
    const float* curb = cur + (size_t)b * CC * NN;
    int nq = t & 3, ci0 = t >> 2;
    #pragma unroll
    for (int q = 0; q < 8; ++q) {
        int ci = ci0 + 64 * q;                 // c-pair 0..511
        int c = 2 * ci;
        const float* p0 = curb + (size_t)c * NN + n0 + 4 * nq;
        float4 f0 = *(const float4*)p0;
        float4 f1 = *(const float4*)(p0 + NN);
        float a0[4] = {f0.x, f0.y, f0.z, f0.w};
        float a1[4] = {f1.x, f1.y, f1.z, f1.w};
        #pragma unroll
        for (int r = 0; r < 4; ++r) {
            int n = 4 * nq + r;
            unsigned pk = (unsigned)f2bf(a0[r]) | ((unsigned)f2bf(a1[r]) << 16);
            *(unsigned*)((char*)XT + n * 2048 + ((((ci >> 2) ^ (n & 7)) << 4) + ((ci & 3) << 2))) = pk;
        }
    }
    __syncthreads();

    // ---- pass A: per-wave independent 16x16 x K=1024 ----
    const char* xbase = (const char*)XT + nrow * 2048;
    const unsigned short* Abase = (mat == 0 ? st16 + (size_t)b * KK * CC : glwh)
                                  + (size_t)(16 * mrow + nrow) * CC + 8 * kq;
    f32x4 acc = {0.f, 0.f, 0.f, 0.f};
    #pragma unroll 8
    for (int cc = 0; cc < 32; ++cc) {
        short8v A = *(const short8v*)(Abase + cc * 32);
        short8v B = *(const short8v*)(xbase + (((cc * 4 + kq) ^ (nrow & 7)) << 4));
        acc = __builtin_amdgcn_mfma_f32_16x16x32_bf16(A, B, acc, 0, 0, 0);
    }

    if (mat == 0) {
        #pragma unroll
        for (int r = 0; r < 4; ++r)
            SIL[16 * mrow + 4 * kq + r][nrow] = acc[r];
    }
    __syncthreads();
    if (t < 16) {
        float s = 0.f;
        #pragma unroll
        for (int k = 0; k < 32; ++k) s += SIL[k][t];
        MS[t] = s * (1.0f / 32.0f);
    }

    // ---- pass B: grouped conv, 8 groups per wave ----
    f32x4 p0 = {0.f, 0.f, 0.f, 0.f}, p1 = {0.f, 0.f, 0.f, 0.f};
    const f32x4 zz = {0.f, 0.f, 0.f, 0.f};
    #pragma unroll
    for (int j = 0; j < 8; ++j) {
        int k = 8 * w + j;
        const unsigned short* gk = gwh + k * 1024 + 8 * kq;
        short8v A0 = *(const short8v*)(gk + nrow * 32);
        short8v A1 = *(const short8v*)(gk + (16 + nrow) * 32);
        short8v B = *(const short8v*)(xbase + (((k * 4 + kq) ^ (nrow & 7)) << 4));
        f32x4 g0 = __builtin_amdgcn_mfma_f32_16x16x32_bf16(A0, B, zz, 0, 0, 0);
        f32x4 g1 = __builtin_amdgcn_mfma_f32_16x16x32_bf16(A1, B, zz, 0, 0, 0);
        float sik = SIL[k][nrow];
        #pragma unroll
        for (int r = 0; r < 4; ++r) {
            p0[r] += sik * fmaxf(g0[r] + GBL[k * 32 + 4 * kq + r], 0.f);
            p1[r] += sik * fmaxf(g1[r] + GBL[k * 32 + 16 + 4 * kq + r], 0.f);
        }
    }
    __syncthreads();                       // all waves done reading XT before alias-write
    *(f32x4*)&PART[w][0][l * 4] = p0;
    *(f32x4*)&PART[w][1][l * 4] = p1;
    __syncthreads();

    // ---- final writes ----
    size_t ob = (size_t)b * 64 * NN + n0 + nrow;
    if (mat == 0) {
        #pragma unroll
        for (int r = 0; r < 4; ++r) {
            int li = l * 4 + r;
            float v = PART[0][mrow][li] + PART[1][mrow][li]
                    + PART[2][mrow][li] + PART[3][mrow][li];
            out[ob + (size_t)(16 * mrow + 4 * kq + r) * NN] = v;
        }
    } else {
        float msv = MS[nrow];
        #pragma unroll
        for (int r = 0; r < 4; ++r) {
            int o = 16 * mrow + 4 * kq + r;
            out[ob + (size_t)(32 + o) * NN] = fmaxf(acc[r] + GLBL[o], 0.f) * msv;
        }
    }
}

extern "C" void kernel_launch(void* const* d_in, const int* in_sizes, int n_in,
                              void* d_out, int out_size, void* d_ws, size_t ws_size,
                              hipStream_t stream) {
    const float* corr = (const float*)d_in[0];   // [B,48,48,48,48]
    const float* cur  = (const float*)d_in[1];   // [B,1024,48,48]
    const float* rm   = (const float*)d_in[2];   // [B,1,384,384]
    const float* gw   = (const float*)d_in[3];   // [32,32,32]
    const float* gb   = (const float*)d_in[4];   // [1024]
    const float* glw  = (const float*)d_in[5];   // [32,1024]
    const float* glb  = (const float*)d_in[6];   // [32]
    float* out = (float*)d_out;
    float* ws  = (float*)d_ws;

    float* mask   = ws;                                   // 18432 f32
    float* scores = mask + BB * MM;                       // 18432 f32
    int*   idx    = (int*)(scores + BB * NN);             // 256 i32
    unsigned short* st16 = (unsigned short*)(idx + 256);  // 262144 u16
    unsigned short* gwh  = st16 + BB * KK * CC;           // 32768 u16
    unsigned short* glwh = gwh + 32768;                   // 32768 u16

    mask_wconv_kernel<<<200, 256, 0, stream>>>(rm, mask, gw, glw, gwh, glwh);
    scores_kernel<<<BB * NN / 4, 256, 0, stream>>>(corr, mask, scores);
    topk_kernel<<<2, 256, 0, stream>>>(scores, idx);
    gather_kernel<<<BB * KK * CC / 256, 256, 0, stream>>>(cur, idx, st16);
    fused_mfma<<<BB * (NN / 16), 256, 0, stream>>>(cur, st16, gwh, glwh, gb, glb, out);
}